// Round 6
// baseline (1204.094 us; speedup 1.0000x reference)
//
#include <hip/hip_runtime.h>

// ---------------------------------------------------------------------------
// VQ-VAE forward. R6:
//  - vq_mfma: software-pipelined staging (register prefetch of step k+1 while
//    MFMA of step k runs) — attacks the 2 TB/s latency-bound L2-miss stream.
//    FP order identical to R5 (argmin bit-stable).
//  - decoder dec1/2/3: parity-MERGED deconv kernel (shared 129-row A tile,
//    3-tap B tile, even+odd accumulators) — halves A staging, 6->3 dispatches.
//    dec0 (U=64, batch-straddling halo) keeps the R5 split kernels.
// Encoder / proj / VQ math unchanged.
// ---------------------------------------------------------------------------

typedef _Float16 half8 __attribute__((ext_vector_type(8)));
typedef _Float16 half4v __attribute__((ext_vector_type(4)));
typedef float f32x4 __attribute__((ext_vector_type(4)));

struct CP2 {
  const _Float16* inH; const _Float16* inL;
  const float* w; const float* bias;
  float* outF; _Float16* outH; _Float16* outL;
  const int* vidx;
  int Ci, lg2Ci, Ti, Co, To, KWO, K2, stride, pad, lg2U, Umask;
};

// SP: input splits (2=hi+lo 3-pass, 1=hi only). PAR: -1 conv, 0 deconv-even
// (tap ko=1), 1 deconv-odd (taps ko=0,2). GATHER: A rows from e1g[vidx].
// OM: 0=f16 hi+lo, 1=f16 hi, 2=f32+hi+lo (proj), 3=f32 (final).
template<int SP, int PAR, bool GATHER, bool RELU, int OM>
__global__ __launch_bounds__(256, SP == 2 ? 3 : 4) void conv_mfma(CP2 p) {
  __shared__ _Float16 As[SP * 128 * 40];
  __shared__ _Float16 Bs[SP * 64 * 40];
  const int tid = threadIdx.x;
  const int wv = tid >> 6;
  const int lane = tid & 63;
  const int m = lane & 15, q = lane >> 4;
  const int btbase = blockIdx.x * 128;
  const int cobase = blockIdx.y * 64;
  f32x4 acc[2][4];
#pragma unroll
  for (int i = 0; i < 2; ++i)
#pragma unroll
    for (int j = 0; j < 4; ++j) acc[i][j] = {0.f, 0.f, 0.f, 0.f};

  const int nkb = p.K2 >> 5;
  for (int kb = 0; kb < nkb; ++kb) {
    const int k0 = kb << 5;
    const int tap = k0 >> p.lg2Ci;
    const int ci0 = k0 & (p.Ci - 1);
    int ko, dt;
    if (PAR == 0)      { ko = 1;       dt = 0; }
    else if (PAR == 1) { ko = 2 * tap; dt = tap; }
    else               { ko = tap;     dt = tap - p.pad; }
    __syncthreads();
    {
      const int cc = tid >> 2, g = tid & 3;
      const int cog = cobase + cc;
      const bool okc = cog < p.Co;
      float wvv[8];
#pragma unroll
      for (int j = 0; j < 8; ++j)
        wvv[j] = okc ? p.w[(cog * p.Ci + ci0 + g * 8 + j) * p.KWO + ko] : 0.f;
      half8 hv, lv;
#pragma unroll
      for (int j = 0; j < 8; ++j) {
        hv[j] = (_Float16)wvv[j];
        if (SP == 2) lv[j] = (_Float16)(wvv[j] - (float)hv[j]);
      }
      *(half8*)&Bs[cc * 40 + g * 8] = hv;
      if (SP == 2) *(half8*)&Bs[64 * 40 + cc * 40 + g * 8] = lv;
    }
#pragma unroll
    for (int it = 0; it < 2; ++it) {
      const int r = it * 64 + (tid >> 2), g = tid & 3;
      const int bt = btbase + r;
      const int b = bt >> p.lg2U, u = bt & p.Umask;
      const int tin = (PAR < 0) ? u * p.stride + dt : u + dt;
      const bool ok = (tin >= 0) && (tin < p.Ti);
      int ai;
      if (GATHER) {
        const int er = ok ? p.vidx[b * p.Ti + tin] : 0;
        ai = er * 256 + ci0 + g * 8;
      } else {
        ai = (b * p.Ti + tin) * p.Ci + ci0 + g * 8;
      }
      const uint4 z = {0u, 0u, 0u, 0u};
      const uint4 vh = ok ? *(const uint4*)&p.inH[ai] : z;
      *(uint4*)&As[r * 40 + g * 8] = vh;
      if (SP == 2) {
        const uint4 vl = ok ? *(const uint4*)&p.inL[ai] : z;
        *(uint4*)&As[128 * 40 + r * 40 + g * 8] = vl;
      }
    }
    __syncthreads();
    half8 a1[2], a2[2];
#pragma unroll
    for (int rt = 0; rt < 2; ++rt) {
      const int row = wv * 32 + rt * 16 + m;
      a1[rt] = *(const half8*)&As[row * 40 + q * 8];
      if (SP == 2) a2[rt] = *(const half8*)&As[128 * 40 + row * 40 + q * 8];
    }
#pragma unroll
    for (int ct = 0; ct < 4; ++ct) {
      const half8 b1 = *(const half8*)&Bs[(ct * 16 + m) * 40 + q * 8];
      half8 b2;
      if (SP == 2) b2 = *(const half8*)&Bs[64 * 40 + (ct * 16 + m) * 40 + q * 8];
#pragma unroll
      for (int rt = 0; rt < 2; ++rt) {
        acc[rt][ct] = __builtin_amdgcn_mfma_f32_16x16x32_f16(a1[rt], b1, acc[rt][ct], 0, 0, 0);
        if (SP == 2) {
          acc[rt][ct] = __builtin_amdgcn_mfma_f32_16x16x32_f16(a2[rt], b1, acc[rt][ct], 0, 0, 0);
          acc[rt][ct] = __builtin_amdgcn_mfma_f32_16x16x32_f16(a1[rt], b2, acc[rt][ct], 0, 0, 0);
        }
      }
    }
  }
#pragma unroll
  for (int ct = 0; ct < 4; ++ct) {
    const int co = cobase + ct * 16 + m;
    if (co < p.Co) {
      const float bv = p.bias[co];
#pragma unroll
      for (int rt = 0; rt < 2; ++rt) {
#pragma unroll
        for (int j = 0; j < 4; ++j) {
          const int row = btbase + wv * 32 + rt * 16 + q * 4 + j;
          const int b = row >> p.lg2U, u = row & p.Umask;
          float v = acc[rt][ct][j] + bv;
          if (RELU) v = fmaxf(v, 0.f);
          const int t = (PAR < 0) ? u : 2 * u + PAR;
          const int oi = (b * p.To + t) * p.Co + co;
          if (OM == 3) {
            p.outF[oi] = v;
          } else if (OM == 1) {
            p.outH[oi] = (_Float16)v;
          } else {
            const _Float16 h = (_Float16)v;
            const _Float16 l = (_Float16)(v - (float)h);
            p.outH[oi] = h; p.outL[oi] = l;
            if (OM == 2) p.outF[oi] = v;
          }
        }
      }
    }
  }
}

struct CPD {
  const _Float16* inH; const float* w; const float* bias;
  float* outF; _Float16* outH;
  int Ci, Ti, Co, To, lg2U, Umask;   // U = Ti, To = 2*Ti; requires Ti >= 128
};

// Parity-merged deconv (k=3,s=2,p=1,op=1). Block 256 thr = 4 waves stacked in
// u; tile 128 u x 64 co -> 256 t x 64 co. A tile 129 rows (halo, batch-edge
// zeroed). B tile: 3 taps. even: W1*A(u); odd: W0*A(u) + W2*A(u+1).
template<bool RELU, bool F32OUT>
__global__ __launch_bounds__(256, 4) void conv_dec(CPD p) {
  __shared__ _Float16 As[129 * 40];
  __shared__ _Float16 Bs[3 * 64 * 40];
  const int tid = threadIdx.x;
  const int wv = tid >> 6;
  const int lane = tid & 63;
  const int m = lane & 15, q = lane >> 4;
  const int btbase = blockIdx.x * 128;
  const int cobase = blockIdx.y * 64;
  const int b0 = btbase >> p.lg2U;
  const int u0 = btbase & p.Umask;
  f32x4 aE[2][4], aO[2][4];
#pragma unroll
  for (int i = 0; i < 2; ++i)
#pragma unroll
    for (int j = 0; j < 4; ++j) { aE[i][j] = {0.f,0.f,0.f,0.f}; aO[i][j] = {0.f,0.f,0.f,0.f}; }

  const int nkb = p.Ci >> 5;
  for (int kb = 0; kb < nkb; ++kb) {
    const int ci0 = kb << 5;
    __syncthreads();
    // B: 3 taps x 64co x 32ci (w layout (co,ci,3); small, L2-hot)
#pragma unroll
    for (int tap = 0; tap < 3; ++tap) {
      const int cc = tid >> 2, g = tid & 3;
      const int cog = cobase + cc;
      half8 hv;
#pragma unroll
      for (int j = 0; j < 8; ++j) {
        const float wv_ = (cog < p.Co) ? p.w[(cog * p.Ci + ci0 + g * 8 + j) * 3 + tap] : 0.f;
        hv[j] = (_Float16)wv_;
      }
      *(half8*)&Bs[tap * 2560 + cc * 40 + g * 8] = hv;
    }
    // A: 129 rows x 32ci
#pragma unroll
    for (int i = 0; i < 3; ++i) {
      const int e = i * 256 + tid;
      const int r = e >> 2, g = e & 3;
      if (r < 129) {
        const int ur = u0 + r;
        const bool ok = ur < p.Ti;
        const uint4 z = {0u, 0u, 0u, 0u};
        const uint4 v = ok ? *(const uint4*)&p.inH[(b0 * p.Ti + ur) * p.Ci + ci0 + g * 8] : z;
        *(uint4*)&As[r * 40 + g * 8] = v;
      }
    }
    __syncthreads();
    half8 a0[2], a1s[2];
#pragma unroll
    for (int rt = 0; rt < 2; ++rt) {
      const int row = wv * 32 + rt * 16 + m;
      a0[rt]  = *(const half8*)&As[row * 40 + q * 8];
      a1s[rt] = *(const half8*)&As[(row + 1) * 40 + q * 8];
    }
#pragma unroll
    for (int ct = 0; ct < 4; ++ct) {
      const int c = ct * 16 + m;
      const half8 w0 = *(const half8*)&Bs[c * 40 + q * 8];
      const half8 w1 = *(const half8*)&Bs[2560 + c * 40 + q * 8];
      const half8 w2 = *(const half8*)&Bs[5120 + c * 40 + q * 8];
#pragma unroll
      for (int rt = 0; rt < 2; ++rt) {
        aE[rt][ct] = __builtin_amdgcn_mfma_f32_16x16x32_f16(a0[rt],  w1, aE[rt][ct], 0, 0, 0);
        aO[rt][ct] = __builtin_amdgcn_mfma_f32_16x16x32_f16(a0[rt],  w0, aO[rt][ct], 0, 0, 0);
        aO[rt][ct] = __builtin_amdgcn_mfma_f32_16x16x32_f16(a1s[rt], w2, aO[rt][ct], 0, 0, 0);
      }
    }
  }
#pragma unroll
  for (int ct = 0; ct < 4; ++ct) {
    const int co = cobase + ct * 16 + m;
    if (co < p.Co) {
      const float bv = p.bias[co];
#pragma unroll
      for (int rt = 0; rt < 2; ++rt) {
#pragma unroll
        for (int j = 0; j < 4; ++j) {
          const int u = u0 + wv * 32 + rt * 16 + q * 4 + j;
          float vE = aE[rt][ct][j] + bv;
          float vO = aO[rt][ct][j] + bv;
          if (RELU) { vE = fmaxf(vE, 0.f); vO = fmaxf(vO, 0.f); }
          const int oiE = (b0 * p.To + 2 * u) * p.Co + co;
          const int oiO = oiE + p.Co;
          if (F32OUT) { p.outF[oiE] = vE; p.outF[oiO] = vO; }
          else        { p.outH[oiE] = (_Float16)vE; p.outH[oiO] = (_Float16)vO; }
        }
      }
    }
  }
}

// split fp32 -> f16 hi + f16 residual
__global__ __launch_bounds__(256) void split_kernel(const float* __restrict__ src,
                                                    _Float16* __restrict__ hi,
                                                    _Float16* __restrict__ lo) {
  const int i = blockIdx.x * 256 + threadIdx.x;
  const float4 v = ((const float4*)src)[i];
  half4v a, b;
  a.x = (_Float16)v.x; b.x = (_Float16)(v.x - (float)a.x);
  a.y = (_Float16)v.y; b.y = (_Float16)(v.y - (float)a.y);
  a.z = (_Float16)v.z; b.z = (_Float16)(v.z - (float)a.z);
  a.w = (_Float16)v.w; b.w = (_Float16)(v.w - (float)a.w);
  ((half4v*)hi)[i] = a;
  ((half4v*)lo)[i] = b;
}

// emb: f16 hi/lo split + |e_k|^2 (fp64), one wave per code.
__global__ __launch_bounds__(256) void emb_prep(const float* __restrict__ emb,
                                                _Float16* __restrict__ hi,
                                                _Float16* __restrict__ lo,
                                                float* __restrict__ nrm) {
  const int k = blockIdx.x * 4 + (threadIdx.x >> 6);
  const int lane = threadIdx.x & 63;
  const int i = k * 64 + lane;
  const float4 v = ((const float4*)emb)[i];
  half4v a, b;
  a.x = (_Float16)v.x; b.x = (_Float16)(v.x - (float)a.x);
  a.y = (_Float16)v.y; b.y = (_Float16)(v.y - (float)a.y);
  a.z = (_Float16)v.z; b.z = (_Float16)(v.z - (float)a.z);
  a.w = (_Float16)v.w; b.w = (_Float16)(v.w - (float)a.w);
  ((half4v*)hi)[i] = a;
  ((half4v*)lo)[i] = b;
  double s = (double)v.x * v.x + (double)v.y * v.y +
             (double)v.z * v.z + (double)v.w * v.w;
  for (int off = 32; off; off >>= 1) s += __shfl_down(s, off);
  if (lane == 0) nrm[k] = (float)s;
}

// VQ argmin, R6: flattened (cc,kb) loop + register prefetch pipeline.
__global__ __launch_bounds__(256, 4) void vq_mfma(const _Float16* __restrict__ z1g,
                                                  const _Float16* __restrict__ z2g,
                                                  const _Float16* __restrict__ e1g,
                                                  const _Float16* __restrict__ e2g,
                                                  const float* __restrict__ nrm,
                                                  float* __restrict__ pbest,
                                                  int* __restrict__ pidx) {
  __shared__ _Float16 lds[4 * 128 * 40];
  const int ZS2 = 5120, ES1 = 10240, ES2 = 15360;
  const int tid = threadIdx.x;
  const int lane = tid & 63;
  const int w = tid >> 6;
  const int m = lane & 15;
  const int q = lane >> 4;
  const int rb = blockIdx.x & 127, seg = blockIdx.x >> 7;
  const int rbase = rb * 128;
  const int w32 = w * 32;
  const int r2 = tid >> 2, s4 = tid & 3;

  float best[8]; int bk[8];
#pragma unroll
  for (int i = 0; i < 8; ++i) { best[i] = 3.4e38f; bk[i] = 0; }

  uint4 pz1[2], pz2[2], pe1[2], pe2[2];
  auto do_loads = [&](int step) {
    const int cc = step >> 3, kb = step & 7;
    const int kof = kb * 32;
    const int cbase = seg * 1024 + cc * 128;
#pragma unroll
    for (int i = 0; i < 2; ++i) {
      const int row = i * 64 + r2;
      const int zg = (rbase + row) * 256 + kof + s4 * 8;
      const int eg = (cbase + row) * 256 + kof + s4 * 8;
      pz1[i] = *(const uint4*)&z1g[zg];
      pz2[i] = *(const uint4*)&z2g[zg];
      pe1[i] = *(const uint4*)&e1g[eg];
      pe2[i] = *(const uint4*)&e2g[eg];
    }
  };

  f32x4 acc[2][8];
  do_loads(0);
  for (int step = 0; step < 64; ++step) {
    const int cc = step >> 3, kb = step & 7;
    const int cbase = seg * 1024 + cc * 128;
    if (kb == 0) {
#pragma unroll
      for (int rt = 0; rt < 2; ++rt)
#pragma unroll
        for (int ct = 0; ct < 8; ++ct) acc[rt][ct] = {0.f, 0.f, 0.f, 0.f};
    }
    __syncthreads();     // prior MFMA reads done
#pragma unroll
    for (int i = 0; i < 2; ++i) {
      const int lo = (i * 64 + r2) * 40 + s4 * 8;
      *(uint4*)&lds[lo]       = pz1[i];
      *(uint4*)&lds[ZS2 + lo] = pz2[i];
      *(uint4*)&lds[ES1 + lo] = pe1[i];
      *(uint4*)&lds[ES2 + lo] = pe2[i];
    }
    if (step < 63) do_loads(step + 1);   // in flight across barrier + MFMA
    __syncthreads();     // LDS visible
    half8 a1[2], a2[2];
#pragma unroll
    for (int rt = 0; rt < 2; ++rt) {
      const int r = w32 + rt * 16 + m;
      a1[rt] = *(const half8*)&lds[r * 40 + q * 8];
      a2[rt] = *(const half8*)&lds[ZS2 + r * 40 + q * 8];
    }
#pragma unroll
    for (int ct = 0; ct < 8; ++ct) {
      const int c = ct * 16 + m;
      const half8 b1 = *(const half8*)&lds[ES1 + c * 40 + q * 8];
      const half8 b2 = *(const half8*)&lds[ES2 + c * 40 + q * 8];
#pragma unroll
      for (int rt = 0; rt < 2; ++rt) {
        acc[rt][ct] = __builtin_amdgcn_mfma_f32_16x16x32_f16(a1[rt], b1, acc[rt][ct], 0, 0, 0);
        acc[rt][ct] = __builtin_amdgcn_mfma_f32_16x16x32_f16(a2[rt], b1, acc[rt][ct], 0, 0, 0);
        acc[rt][ct] = __builtin_amdgcn_mfma_f32_16x16x32_f16(a1[rt], b2, acc[rt][ct], 0, 0, 0);
      }
    }
    if (kb == 7) {
#pragma unroll
      for (int ct = 0; ct < 8; ++ct) {
        const int k = cbase + ct * 16 + m;
        const float nv = nrm[k];
#pragma unroll
        for (int rt = 0; rt < 2; ++rt)
#pragma unroll
          for (int rg = 0; rg < 4; ++rg) {
            const float d = nv - 2.f * acc[rt][ct][rg];
            const int slot = rt * 4 + rg;
            if (d < best[slot] || (d == best[slot] && k < bk[slot])) {
              best[slot] = d; bk[slot] = k;
            }
          }
      }
    }
  }
#pragma unroll
  for (int slot = 0; slot < 8; ++slot) {
    float bv = best[slot]; int kv = bk[slot];
    for (int off = 1; off < 16; off <<= 1) {
      const float ob = __shfl_xor(bv, off);
      const int ok = __shfl_xor(kv, off);
      if (ob < bv || (ob == bv && ok < kv)) { bv = ob; kv = ok; }
    }
    if (m == 0) {
      const int row = rbase + w32 + (slot >> 2) * 16 + q * 4 + (slot & 3);
      pbest[seg * 16384 + row] = bv;
      pidx[seg * 16384 + row] = kv;
    }
  }
}

__global__ void merge_kernel(const float* __restrict__ pbest, const int* __restrict__ pidx,
                             int* __restrict__ vidx, float* __restrict__ out_idx,
                             float* __restrict__ lacc) {
  const int n = blockIdx.x * 256 + threadIdx.x;
  float bv = pbest[n]; int kv = pidx[n];
#pragma unroll
  for (int s = 1; s < 8; ++s) {
    const float ob = pbest[s * 16384 + n];
    const int ok = pidx[s * 16384 + n];
    if (ob < bv || (ob == bv && ok < kv)) { bv = ob; kv = ok; }
  }
  vidx[n] = kv;
  out_idx[n] = (float)kv;
  if (n == 0) *lacc = 0.f;
}

__global__ __launch_bounds__(256) void loss_kernel(const float* __restrict__ zf,
                                                   const float* __restrict__ emb,
                                                   const int* __restrict__ vidx,
                                                   float* __restrict__ lacc) {
  const int e0 = (blockIdx.x * 256 + threadIdx.x) * 4;
  const int n = e0 >> 8, c = e0 & 255;
  const float4 z4 = *(const float4*)&zf[e0];
  const float4 q4 = *(const float4*)&emb[vidx[n] * 256 + c];
  const float dx = z4.x - q4.x, dy = z4.y - q4.y, dz = z4.z - q4.z, dw = z4.w - q4.w;
  float s = dx * dx + dy * dy + dz * dz + dw * dw;
  for (int off = 32; off; off >>= 1) s += __shfl_down(s, off);
  __shared__ float red[4];
  if ((threadIdx.x & 63) == 0) red[threadIdx.x >> 6] = s;
  __syncthreads();
  if (threadIdx.x == 0) atomicAdd(lacc, red[0] + red[1] + red[2] + red[3]);
}

__global__ void fin_kernel(const float* __restrict__ lacc, float* __restrict__ out, int loff) {
  if (threadIdx.x == 0) {
    const float l = *lacc * (1.f / 4194304.f);
    out[loff] = l;
    out[loff + 1] = l;
  }
}

extern "C" void kernel_launch(void* const* d_in, const int* in_sizes, int n_in,
                              void* d_out, int out_size, void* d_ws, size_t ws_size,
                              hipStream_t stream) {
  const float* x   = (const float*)d_in[0];
  const float* ew0 = (const float*)d_in[1];  const float* eb0 = (const float*)d_in[2];
  const float* ew1 = (const float*)d_in[3];  const float* eb1 = (const float*)d_in[4];
  const float* ew2 = (const float*)d_in[5];  const float* eb2 = (const float*)d_in[6];
  const float* pw  = (const float*)d_in[7];  const float* pb  = (const float*)d_in[8];
  const float* emb = (const float*)d_in[9];
  const float* dw0 = (const float*)d_in[10]; const float* db0 = (const float*)d_in[11];
  const float* dw1 = (const float*)d_in[12]; const float* db1 = (const float*)d_in[13];
  const float* dw2 = (const float*)d_in[14]; const float* db2 = (const float*)d_in[15];
  const float* dw3 = (const float*)d_in[16]; const float* db3 = (const float*)d_in[17];
  float* ws  = (float*)d_ws;
  float* out = (float*)d_out;

  const int A0 = 0, B0 = 4194304, C0 = 8388608, TL = 12582912;
  _Float16* xh  = (_Float16*)(ws + A0);
  _Float16* xl  = xh + 4194304;
  _Float16* h1h = (_Float16*)(ws + B0);
  _Float16* h1l = h1h + 4194304;
  _Float16* h2h = (_Float16*)(ws + A0);
  _Float16* h2l = h2h + 4194304;
  _Float16* h3h = (_Float16*)(ws + B0);
  _Float16* h3l = h3h + 4194304;
  float*    zf  = ws + C0;
  _Float16* z1g = (_Float16*)(ws + A0);
  _Float16* z2g = z1g + 4194304;
  _Float16* e1g = (_Float16*)(ws + B0);
  _Float16* e2g = e1g + 2097152;
  float* pbest = ws + B0 + 2097152;
  int*   pidx  = (int*)(ws + B0 + 2097152 + 131072);
  _Float16* d1h = (_Float16*)(ws + C0);
  _Float16* d2h = (_Float16*)(ws + A0);
  _Float16* d3h = (_Float16*)(ws + B0);
  float* nrm  = ws + TL;
  int*   vidx = (int*)(ws + TL + 8192);
  float* lacc = ws + TL + 8192 + 16384;

  const int idx_off  = out_size - 16384;
  const int loss_off = out_size - 16386;

  // ---- encoder (3-pass f16 split MFMA) ----
  split_kernel<<<4096, 256, 0, stream>>>(x, xh, xl);

  CP2 p; p.vidx = nullptr;
  p.inH = xh; p.inL = xl; p.w = ew0; p.bias = eb0;
  p.outF = nullptr; p.outH = h1h; p.outL = h1l;
  p.Ci = 32; p.lg2Ci = 5; p.Ti = 512; p.Co = 64; p.To = 256; p.KWO = 3;
  p.K2 = 96; p.stride = 2; p.pad = 1; p.lg2U = 8; p.Umask = 255;
  conv_mfma<2, -1, false, true, 0><<<dim3(512, 1), 256, 0, stream>>>(p);

  p.inH = h1h; p.inL = h1l; p.w = ew1; p.bias = eb1; p.outH = h2h; p.outL = h2l;
  p.Ci = 64; p.lg2Ci = 6; p.Ti = 256; p.Co = 128; p.To = 128; p.K2 = 192;
  p.lg2U = 7; p.Umask = 127;
  conv_mfma<2, -1, false, true, 0><<<dim3(256, 2), 256, 0, stream>>>(p);

  p.inH = h2h; p.inL = h2l; p.w = ew2; p.bias = eb2; p.outH = h3h; p.outL = h3l;
  p.Ci = 128; p.lg2Ci = 7; p.Ti = 128; p.Co = 256; p.To = 64; p.K2 = 384;
  p.lg2U = 6; p.Umask = 63;
  conv_mfma<2, -1, false, true, 0><<<dim3(128, 4), 256, 0, stream>>>(p);

  p.inH = h3h; p.inL = h3l; p.w = pw; p.bias = pb;
  p.outF = zf; p.outH = z1g; p.outL = z2g;
  p.Ci = 256; p.lg2Ci = 8; p.Ti = 64; p.Co = 256; p.To = 64; p.KWO = 1;
  p.K2 = 256; p.stride = 1; p.pad = 0; p.lg2U = 6; p.Umask = 63;
  conv_mfma<2, -1, false, false, 2><<<dim3(128, 4), 256, 0, stream>>>(p);

  // ---- VQ ----
  emb_prep<<<2048, 256, 0, stream>>>(emb, e1g, e2g, nrm);
  vq_mfma<<<1024, 256, 0, stream>>>(z1g, z2g, e1g, e2g, nrm, pbest, pidx);
  merge_kernel<<<64, 256, 0, stream>>>(pbest, pidx, vidx, out + idx_off, lacc);
  loss_kernel<<<4096, 256, 0, stream>>>(zf, emb, vidx, lacc);
  fin_kernel<<<1, 64, 0, stream>>>(lacc, out, loss_off);

  // ---- decoder ----
  // dec0 (U=64): R5 split kernels with e1g[vidx] gather
  p.inH = e1g; p.inL = nullptr; p.w = dw0; p.bias = db0;
  p.outF = nullptr; p.outH = d1h; p.outL = nullptr; p.vidx = vidx;
  p.Ci = 256; p.lg2Ci = 8; p.Ti = 64; p.Co = 256; p.To = 128; p.KWO = 3;
  p.lg2U = 6; p.Umask = 63;
  p.K2 = 256; conv_mfma<1, 0, true, true, 1><<<dim3(128, 4), 256, 0, stream>>>(p);
  p.K2 = 512; conv_mfma<1, 1, true, true, 1><<<dim3(128, 4), 256, 0, stream>>>(p);

  // dec1..dec3: parity-merged
  CPD d;
  d.inH = d1h; d.w = dw1; d.bias = db1; d.outF = nullptr; d.outH = d2h;
  d.Ci = 256; d.Ti = 128; d.Co = 128; d.To = 256; d.lg2U = 7; d.Umask = 127;
  conv_dec<true, false><<<dim3(256, 2), 256, 0, stream>>>(d);

  d.inH = d2h; d.w = dw2; d.bias = db2; d.outH = d3h;
  d.Ci = 128; d.Ti = 256; d.Co = 64; d.To = 512; d.lg2U = 8; d.Umask = 255;
  conv_dec<true, false><<<dim3(512, 1), 256, 0, stream>>>(d);

  d.inH = d3h; d.w = dw3; d.bias = db3; d.outF = out; d.outH = nullptr;
  d.Ci = 64; d.Ti = 512; d.Co = 32; d.To = 1024; d.lg2U = 9; d.Umask = 511;
  conv_dec<false, true><<<dim3(1024, 1), 256, 0, stream>>>(d);
}

// Round 7
// 906.986 us; speedup vs baseline: 1.3276x; 1.3276x over previous
//
#include <hip/hip_runtime.h>

// ---------------------------------------------------------------------------
// VQ-VAE forward. R7: consolidation.
//  - vq_mfma reverted to the R5 kernel (R6's prefetch arrays were captured
//    by-reference in a lambda -> scratch spill -> 2.1 GB of scratch WRITE).
//  - enc0 stages A straight from fp32 x with inline hi/lo split (split_kernel
//    deleted).
//  - zf (fp32 z_e) eliminated: proj emits z1g/z2g only; loss uses z1+z2.
//  - decoder: dec1-3 merged parity kernel (R6, proven); dec0 stays split
//    (128-row tiles span two batches; merged halo slot would need to be both
//    real x[u] and zero x[u+1] at interior batch boundaries).
// ---------------------------------------------------------------------------

typedef _Float16 half8 __attribute__((ext_vector_type(8)));
typedef _Float16 half4v __attribute__((ext_vector_type(4)));
typedef float f32x4 __attribute__((ext_vector_type(4)));

struct CP2 {
  const _Float16* inH; const _Float16* inL; const float* inF;
  const float* w; const float* bias;
  float* outF; _Float16* outH; _Float16* outL;
  const int* vidx;
  int Ci, lg2Ci, Ti, Co, To, KWO, K2, stride, pad, lg2U, Umask;
};

// SP: input splits (2=hi+lo 3-pass, 1=hi only). PAR: -1 conv, 0 deconv-even
// (tap ko=1), 1 deconv-odd (taps ko=0,2). GATHER: A rows from e1g[vidx].
// OM: 0=f16 hi+lo, 1=f16 hi, 3=f32. INF32: stage A from fp32 src w/ inline split.
template<int SP, int PAR, bool GATHER, bool RELU, int OM, bool INF32>
__global__ __launch_bounds__(256, SP == 2 ? 3 : 4) void conv_mfma(CP2 p) {
  __shared__ _Float16 As[SP * 128 * 40];
  __shared__ _Float16 Bs[SP * 64 * 40];
  const int tid = threadIdx.x;
  const int wv = tid >> 6;
  const int lane = tid & 63;
  const int m = lane & 15, q = lane >> 4;
  const int btbase = blockIdx.x * 128;
  const int cobase = blockIdx.y * 64;
  f32x4 acc[2][4];
#pragma unroll
  for (int i = 0; i < 2; ++i)
#pragma unroll
    for (int j = 0; j < 4; ++j) acc[i][j] = {0.f, 0.f, 0.f, 0.f};

  const int nkb = p.K2 >> 5;
  for (int kb = 0; kb < nkb; ++kb) {
    const int k0 = kb << 5;
    const int tap = k0 >> p.lg2Ci;
    const int ci0 = k0 & (p.Ci - 1);
    int ko, dt;
    if (PAR == 0)      { ko = 1;       dt = 0; }
    else if (PAR == 1) { ko = 2 * tap; dt = tap; }
    else               { ko = tap;     dt = tap - p.pad; }
    __syncthreads();
    // ---- stage B: 64co x 32k, fp32 weights split to f16 hi(/lo)
    {
      const int cc = tid >> 2, g = tid & 3;
      const int cog = cobase + cc;
      const bool okc = cog < p.Co;
      float wvv[8];
#pragma unroll
      for (int j = 0; j < 8; ++j)
        wvv[j] = okc ? p.w[(cog * p.Ci + ci0 + g * 8 + j) * p.KWO + ko] : 0.f;
      half8 hv, lv;
#pragma unroll
      for (int j = 0; j < 8; ++j) {
        hv[j] = (_Float16)wvv[j];
        if (SP == 2) lv[j] = (_Float16)(wvv[j] - (float)hv[j]);
      }
      *(half8*)&Bs[cc * 40 + g * 8] = hv;
      if (SP == 2) *(half8*)&Bs[64 * 40 + cc * 40 + g * 8] = lv;
    }
    // ---- stage A: 128bt x 32k
#pragma unroll
    for (int it = 0; it < 2; ++it) {
      const int r = it * 64 + (tid >> 2), g = tid & 3;
      const int bt = btbase + r;
      const int b = bt >> p.lg2U, u = bt & p.Umask;
      const int tin = (PAR < 0) ? u * p.stride + dt : u + dt;
      const bool ok = (tin >= 0) && (tin < p.Ti);
      int ai;
      if (GATHER) {
        const int er = ok ? p.vidx[b * p.Ti + tin] : 0;
        ai = er * 256 + ci0 + g * 8;
      } else {
        ai = (b * p.Ti + tin) * p.Ci + ci0 + g * 8;
      }
      if (INF32) {
        float vv[8];
#pragma unroll
        for (int j = 0; j < 8; ++j) vv[j] = ok ? p.inF[ai + j] : 0.f;
        half8 hv, lv;
#pragma unroll
        for (int j = 0; j < 8; ++j) {
          hv[j] = (_Float16)vv[j];
          lv[j] = (_Float16)(vv[j] - (float)hv[j]);
        }
        *(half8*)&As[r * 40 + g * 8] = hv;
        if (SP == 2) *(half8*)&As[128 * 40 + r * 40 + g * 8] = lv;
      } else {
        const uint4 z = {0u, 0u, 0u, 0u};
        const uint4 vh = ok ? *(const uint4*)&p.inH[ai] : z;
        *(uint4*)&As[r * 40 + g * 8] = vh;
        if (SP == 2) {
          const uint4 vl = ok ? *(const uint4*)&p.inL[ai] : z;
          *(uint4*)&As[128 * 40 + r * 40 + g * 8] = vl;
        }
      }
    }
    __syncthreads();
    half8 a1[2], a2[2];
#pragma unroll
    for (int rt = 0; rt < 2; ++rt) {
      const int row = wv * 32 + rt * 16 + m;
      a1[rt] = *(const half8*)&As[row * 40 + q * 8];
      if (SP == 2) a2[rt] = *(const half8*)&As[128 * 40 + row * 40 + q * 8];
    }
#pragma unroll
    for (int ct = 0; ct < 4; ++ct) {
      const half8 b1 = *(const half8*)&Bs[(ct * 16 + m) * 40 + q * 8];
      half8 b2;
      if (SP == 2) b2 = *(const half8*)&Bs[64 * 40 + (ct * 16 + m) * 40 + q * 8];
#pragma unroll
      for (int rt = 0; rt < 2; ++rt) {
        acc[rt][ct] = __builtin_amdgcn_mfma_f32_16x16x32_f16(a1[rt], b1, acc[rt][ct], 0, 0, 0);
        if (SP == 2) {
          acc[rt][ct] = __builtin_amdgcn_mfma_f32_16x16x32_f16(a2[rt], b1, acc[rt][ct], 0, 0, 0);
          acc[rt][ct] = __builtin_amdgcn_mfma_f32_16x16x32_f16(a1[rt], b2, acc[rt][ct], 0, 0, 0);
        }
      }
    }
  }
  // ---- epilogue: C layout col=lane&15, row=q*4+reg
#pragma unroll
  for (int ct = 0; ct < 4; ++ct) {
    const int co = cobase + ct * 16 + m;
    if (co < p.Co) {
      const float bv = p.bias[co];
#pragma unroll
      for (int rt = 0; rt < 2; ++rt) {
#pragma unroll
        for (int j = 0; j < 4; ++j) {
          const int row = btbase + wv * 32 + rt * 16 + q * 4 + j;
          const int b = row >> p.lg2U, u = row & p.Umask;
          float v = acc[rt][ct][j] + bv;
          if (RELU) v = fmaxf(v, 0.f);
          const int t = (PAR < 0) ? u : 2 * u + PAR;
          const int oi = (b * p.To + t) * p.Co + co;
          if (OM == 3) {
            p.outF[oi] = v;
          } else if (OM == 1) {
            p.outH[oi] = (_Float16)v;
          } else {
            const _Float16 h = (_Float16)v;
            const _Float16 l = (_Float16)(v - (float)h);
            p.outH[oi] = h; p.outL[oi] = l;
          }
        }
      }
    }
  }
}

struct CPD {
  const _Float16* inH; const float* w; const float* bias;
  float* outF; _Float16* outH;
  int Ci, Ti, Co, To, lg2U, Umask;   // requires 128 | Ti (tile within batch)
};

// Parity-merged deconv (k=3,s=2,p=1,op=1). 128 u x 64 co tile -> 256 t x 64 co.
// A tile 129 rows (halo, batch-edge zeroed via ur<Ti).
template<bool RELU, bool F32OUT>
__global__ __launch_bounds__(256, 4) void conv_dec(CPD p) {
  __shared__ _Float16 As[129 * 40];
  __shared__ _Float16 Bs[3 * 64 * 40];
  const int tid = threadIdx.x;
  const int wv = tid >> 6;
  const int lane = tid & 63;
  const int m = lane & 15, q = lane >> 4;
  const int btbase = blockIdx.x * 128;
  const int cobase = blockIdx.y * 64;
  const int b0 = btbase >> p.lg2U;
  const int u0 = btbase & p.Umask;
  f32x4 aE[2][4], aO[2][4];
#pragma unroll
  for (int i = 0; i < 2; ++i)
#pragma unroll
    for (int j = 0; j < 4; ++j) { aE[i][j] = {0.f,0.f,0.f,0.f}; aO[i][j] = {0.f,0.f,0.f,0.f}; }

  const int nkb = p.Ci >> 5;
  for (int kb = 0; kb < nkb; ++kb) {
    const int ci0 = kb << 5;
    __syncthreads();
#pragma unroll
    for (int tap = 0; tap < 3; ++tap) {
      const int cc = tid >> 2, g = tid & 3;
      const int cog = cobase + cc;
      half8 hv;
#pragma unroll
      for (int j = 0; j < 8; ++j) {
        const float wv_ = (cog < p.Co) ? p.w[(cog * p.Ci + ci0 + g * 8 + j) * 3 + tap] : 0.f;
        hv[j] = (_Float16)wv_;
      }
      *(half8*)&Bs[tap * 2560 + cc * 40 + g * 8] = hv;
    }
#pragma unroll
    for (int i = 0; i < 3; ++i) {
      const int e = i * 256 + tid;
      const int r = e >> 2, g = e & 3;
      if (r < 129) {
        const int ur = u0 + r;
        const bool ok = ur < p.Ti;
        const uint4 z = {0u, 0u, 0u, 0u};
        const uint4 v = ok ? *(const uint4*)&p.inH[(b0 * p.Ti + ur) * p.Ci + ci0 + g * 8] : z;
        *(uint4*)&As[r * 40 + g * 8] = v;
      }
    }
    __syncthreads();
    half8 a0[2], a1s[2];
#pragma unroll
    for (int rt = 0; rt < 2; ++rt) {
      const int row = wv * 32 + rt * 16 + m;
      a0[rt]  = *(const half8*)&As[row * 40 + q * 8];
      a1s[rt] = *(const half8*)&As[(row + 1) * 40 + q * 8];
    }
#pragma unroll
    for (int ct = 0; ct < 4; ++ct) {
      const int c = ct * 16 + m;
      const half8 w0 = *(const half8*)&Bs[c * 40 + q * 8];
      const half8 w1 = *(const half8*)&Bs[2560 + c * 40 + q * 8];
      const half8 w2 = *(const half8*)&Bs[5120 + c * 40 + q * 8];
#pragma unroll
      for (int rt = 0; rt < 2; ++rt) {
        aE[rt][ct] = __builtin_amdgcn_mfma_f32_16x16x32_f16(a0[rt],  w1, aE[rt][ct], 0, 0, 0);
        aO[rt][ct] = __builtin_amdgcn_mfma_f32_16x16x32_f16(a0[rt],  w0, aO[rt][ct], 0, 0, 0);
        aO[rt][ct] = __builtin_amdgcn_mfma_f32_16x16x32_f16(a1s[rt], w2, aO[rt][ct], 0, 0, 0);
      }
    }
  }
#pragma unroll
  for (int ct = 0; ct < 4; ++ct) {
    const int co = cobase + ct * 16 + m;
    if (co < p.Co) {
      const float bv = p.bias[co];
#pragma unroll
      for (int rt = 0; rt < 2; ++rt) {
#pragma unroll
        for (int j = 0; j < 4; ++j) {
          const int u = u0 + wv * 32 + rt * 16 + q * 4 + j;
          float vE = aE[rt][ct][j] + bv;
          float vO = aO[rt][ct][j] + bv;
          if (RELU) { vE = fmaxf(vE, 0.f); vO = fmaxf(vO, 0.f); }
          const int oiE = (b0 * p.To + 2 * u) * p.Co + co;
          const int oiO = oiE + p.Co;
          if (F32OUT) { p.outF[oiE] = vE; p.outF[oiO] = vO; }
          else        { p.outH[oiE] = (_Float16)vE; p.outH[oiO] = (_Float16)vO; }
        }
      }
    }
  }
}

// emb: f16 hi/lo split + |e_k|^2 (fp64), one wave per code.
__global__ __launch_bounds__(256) void emb_prep(const float* __restrict__ emb,
                                                _Float16* __restrict__ hi,
                                                _Float16* __restrict__ lo,
                                                float* __restrict__ nrm) {
  const int k = blockIdx.x * 4 + (threadIdx.x >> 6);
  const int lane = threadIdx.x & 63;
  const int i = k * 64 + lane;
  const float4 v = ((const float4*)emb)[i];
  half4v a, b;
  a.x = (_Float16)v.x; b.x = (_Float16)(v.x - (float)a.x);
  a.y = (_Float16)v.y; b.y = (_Float16)(v.y - (float)a.y);
  a.z = (_Float16)v.z; b.z = (_Float16)(v.z - (float)a.z);
  a.w = (_Float16)v.w; b.w = (_Float16)(v.w - (float)a.w);
  ((half4v*)hi)[i] = a;
  ((half4v*)lo)[i] = b;
  double s = (double)v.x * v.x + (double)v.y * v.y +
             (double)v.z * v.z + (double)v.w * v.w;
  for (int off = 32; off; off >>= 1) s += __shfl_down(s, off);
  if (lane == 0) nrm[k] = (float)s;
}

// VQ argmin via MFMA — R5 kernel verbatim (proven 394 us).
__global__ __launch_bounds__(256, 4) void vq_mfma(const _Float16* __restrict__ z1g,
                                                  const _Float16* __restrict__ z2g,
                                                  const _Float16* __restrict__ e1g,
                                                  const _Float16* __restrict__ e2g,
                                                  const float* __restrict__ nrm,
                                                  float* __restrict__ pbest,
                                                  int* __restrict__ pidx) {
  __shared__ _Float16 lds[4 * 128 * 40];
  const int ZS2 = 5120, ES1 = 10240, ES2 = 15360;
  const int tid = threadIdx.x;
  const int lane = tid & 63;
  const int w = tid >> 6;
  const int m = lane & 15;
  const int q = lane >> 4;
  const int rb = blockIdx.x & 127, seg = blockIdx.x >> 7;
  const int rbase = rb * 128;
  const int w32 = w * 32;
  const int r2 = tid >> 2, s4 = tid & 3;

  float best[8]; int bk[8];
#pragma unroll
  for (int i = 0; i < 8; ++i) { best[i] = 3.4e38f; bk[i] = 0; }

  for (int cc = 0; cc < 8; ++cc) {
    const int cbase = seg * 1024 + cc * 128;
    f32x4 acc[2][8];
#pragma unroll
    for (int rt = 0; rt < 2; ++rt)
#pragma unroll
      for (int ct = 0; ct < 8; ++ct) acc[rt][ct] = {0.f, 0.f, 0.f, 0.f};

    for (int kb = 0; kb < 8; ++kb) {
      const int kof = kb * 32;
      __syncthreads();
#pragma unroll
      for (int i = 0; i < 2; ++i) {
        const int row = i * 64 + r2;
        const int zg = (rbase + row) * 256 + kof + s4 * 8;
        const int eg = (cbase + row) * 256 + kof + s4 * 8;
        const int lo = row * 40 + s4 * 8;
        *(uint4*)&lds[lo]       = *(const uint4*)&z1g[zg];
        *(uint4*)&lds[ZS2 + lo] = *(const uint4*)&z2g[zg];
        *(uint4*)&lds[ES1 + lo] = *(const uint4*)&e1g[eg];
        *(uint4*)&lds[ES2 + lo] = *(const uint4*)&e2g[eg];
      }
      __syncthreads();
      half8 a1[2], a2[2];
#pragma unroll
      for (int rt = 0; rt < 2; ++rt) {
        const int r = w32 + rt * 16 + m;
        a1[rt] = *(const half8*)&lds[r * 40 + q * 8];
        a2[rt] = *(const half8*)&lds[ZS2 + r * 40 + q * 8];
      }
#pragma unroll
      for (int ct = 0; ct < 8; ++ct) {
        const int c = ct * 16 + m;
        const half8 b1 = *(const half8*)&lds[ES1 + c * 40 + q * 8];
        const half8 b2 = *(const half8*)&lds[ES2 + c * 40 + q * 8];
#pragma unroll
        for (int rt = 0; rt < 2; ++rt) {
          acc[rt][ct] = __builtin_amdgcn_mfma_f32_16x16x32_f16(a1[rt], b1, acc[rt][ct], 0, 0, 0);
          acc[rt][ct] = __builtin_amdgcn_mfma_f32_16x16x32_f16(a2[rt], b1, acc[rt][ct], 0, 0, 0);
          acc[rt][ct] = __builtin_amdgcn_mfma_f32_16x16x32_f16(a1[rt], b2, acc[rt][ct], 0, 0, 0);
        }
      }
    }
#pragma unroll
    for (int ct = 0; ct < 8; ++ct) {
      const int k = cbase + ct * 16 + m;
      const float nv = nrm[k];
#pragma unroll
      for (int rt = 0; rt < 2; ++rt)
#pragma unroll
        for (int rg = 0; rg < 4; ++rg) {
          const float d = nv - 2.f * acc[rt][ct][rg];
          const int slot = rt * 4 + rg;
          if (d < best[slot] || (d == best[slot] && k < bk[slot])) {
            best[slot] = d; bk[slot] = k;
          }
        }
    }
  }
#pragma unroll
  for (int slot = 0; slot < 8; ++slot) {
    float bv = best[slot]; int kv = bk[slot];
    for (int off = 1; off < 16; off <<= 1) {
      const float ob = __shfl_xor(bv, off);
      const int ok = __shfl_xor(kv, off);
      if (ob < bv || (ob == bv && ok < kv)) { bv = ob; kv = ok; }
    }
    if (m == 0) {
      const int row = rbase + w32 + (slot >> 2) * 16 + q * 4 + (slot & 3);
      pbest[seg * 16384 + row] = bv;
      pidx[seg * 16384 + row] = kv;
    }
  }
}

__global__ void merge_kernel(const float* __restrict__ pbest, const int* __restrict__ pidx,
                             int* __restrict__ vidx, float* __restrict__ out_idx,
                             float* __restrict__ lacc) {
  const int n = blockIdx.x * 256 + threadIdx.x;
  float bv = pbest[n]; int kv = pidx[n];
#pragma unroll
  for (int s = 1; s < 8; ++s) {
    const float ob = pbest[s * 16384 + n];
    const int ok = pidx[s * 16384 + n];
    if (ob < bv || (ob == bv && ok < kv)) { bv = ob; kv = ok; }
  }
  vidx[n] = kv;
  out_idx[n] = (float)kv;
  if (n == 0) *lacc = 0.f;
}

// loss from z1+z2 (== fp32 z_e to 2^-22 rel; loss tolerance is 2%)
__global__ __launch_bounds__(256) void loss_kernel(const _Float16* __restrict__ z1g,
                                                   const _Float16* __restrict__ z2g,
                                                   const float* __restrict__ emb,
                                                   const int* __restrict__ vidx,
                                                   float* __restrict__ lacc) {
  const int g4 = blockIdx.x * 256 + threadIdx.x;   // 4 elems/thread
  const int e0 = g4 * 4;
  const int n = e0 >> 8, c = e0 & 255;
  const half4v a = ((const half4v*)z1g)[g4];
  const half4v b = ((const half4v*)z2g)[g4];
  const float4 q4 = *(const float4*)&emb[vidx[n] * 256 + c];
  const float dx = ((float)a.x + (float)b.x) - q4.x;
  const float dy = ((float)a.y + (float)b.y) - q4.y;
  const float dz = ((float)a.z + (float)b.z) - q4.z;
  const float dw = ((float)a.w + (float)b.w) - q4.w;
  float s = dx * dx + dy * dy + dz * dz + dw * dw;
  for (int off = 32; off; off >>= 1) s += __shfl_down(s, off);
  __shared__ float red[4];
  if ((threadIdx.x & 63) == 0) red[threadIdx.x >> 6] = s;
  __syncthreads();
  if (threadIdx.x == 0) atomicAdd(lacc, red[0] + red[1] + red[2] + red[3]);
}

__global__ void fin_kernel(const float* __restrict__ lacc, float* __restrict__ out, int loff) {
  if (threadIdx.x == 0) {
    const float l = *lacc * (1.f / 4194304.f);
    out[loff] = l;
    out[loff + 1] = l;
  }
}

extern "C" void kernel_launch(void* const* d_in, const int* in_sizes, int n_in,
                              void* d_out, int out_size, void* d_ws, size_t ws_size,
                              hipStream_t stream) {
  const float* x   = (const float*)d_in[0];
  const float* ew0 = (const float*)d_in[1];  const float* eb0 = (const float*)d_in[2];
  const float* ew1 = (const float*)d_in[3];  const float* eb1 = (const float*)d_in[4];
  const float* ew2 = (const float*)d_in[5];  const float* eb2 = (const float*)d_in[6];
  const float* pw  = (const float*)d_in[7];  const float* pb  = (const float*)d_in[8];
  const float* emb = (const float*)d_in[9];
  const float* dw0 = (const float*)d_in[10]; const float* db0 = (const float*)d_in[11];
  const float* dw1 = (const float*)d_in[12]; const float* db1 = (const float*)d_in[13];
  const float* dw2 = (const float*)d_in[14]; const float* db2 = (const float*)d_in[15];
  const float* dw3 = (const float*)d_in[16]; const float* db3 = (const float*)d_in[17];
  float* ws  = (float*)d_ws;
  float* out = (float*)d_out;

  const int A0 = 0, B0 = 4194304, C0 = 8388608, TL = 12582912;
  _Float16* h1h = (_Float16*)(ws + B0);
  _Float16* h1l = h1h + 4194304;
  _Float16* h2h = (_Float16*)(ws + A0);
  _Float16* h2l = h2h + 4194304;
  _Float16* h3h = (_Float16*)(ws + B0);
  _Float16* h3l = h3h + 4194304;
  _Float16* z1g = (_Float16*)(ws + A0);
  _Float16* z2g = z1g + 4194304;
  _Float16* e1g = (_Float16*)(ws + B0);
  _Float16* e2g = e1g + 2097152;
  float* pbest = ws + B0 + 2097152;
  int*   pidx  = (int*)(ws + B0 + 2097152 + 131072);
  _Float16* d1h = (_Float16*)(ws + C0);
  _Float16* d2h = (_Float16*)(ws + A0);
  _Float16* d3h = (_Float16*)(ws + B0);
  float* nrm  = ws + TL;
  int*   vidx = (int*)(ws + TL + 8192);
  float* lacc = ws + TL + 8192 + 16384;

  const int idx_off  = out_size - 16384;
  const int loss_off = out_size - 16386;

  CP2 p; p.vidx = nullptr; p.inF = nullptr; p.inH = nullptr; p.inL = nullptr;
  p.outF = nullptr; p.outH = nullptr; p.outL = nullptr;

  // ---- encoder (3-pass f16 split MFMA; enc0 splits x inline) ----
  p.inF = x; p.w = ew0; p.bias = eb0; p.outH = h1h; p.outL = h1l;
  p.Ci = 32; p.lg2Ci = 5; p.Ti = 512; p.Co = 64; p.To = 256; p.KWO = 3;
  p.K2 = 96; p.stride = 2; p.pad = 1; p.lg2U = 8; p.Umask = 255;
  conv_mfma<2, -1, false, true, 0, true><<<dim3(512, 1), 256, 0, stream>>>(p);

  p.inF = nullptr;
  p.inH = h1h; p.inL = h1l; p.w = ew1; p.bias = eb1; p.outH = h2h; p.outL = h2l;
  p.Ci = 64; p.lg2Ci = 6; p.Ti = 256; p.Co = 128; p.To = 128; p.K2 = 192;
  p.lg2U = 7; p.Umask = 127;
  conv_mfma<2, -1, false, true, 0, false><<<dim3(256, 2), 256, 0, stream>>>(p);

  p.inH = h2h; p.inL = h2l; p.w = ew2; p.bias = eb2; p.outH = h3h; p.outL = h3l;
  p.Ci = 128; p.lg2Ci = 7; p.Ti = 128; p.Co = 256; p.To = 64; p.K2 = 384;
  p.lg2U = 6; p.Umask = 63;
  conv_mfma<2, -1, false, true, 0, false><<<dim3(128, 4), 256, 0, stream>>>(p);

  // proj: emits z1g/z2g only (zf eliminated)
  p.inH = h3h; p.inL = h3l; p.w = pw; p.bias = pb;
  p.outH = z1g; p.outL = z2g;
  p.Ci = 256; p.lg2Ci = 8; p.Ti = 64; p.Co = 256; p.To = 64; p.KWO = 1;
  p.K2 = 256; p.stride = 1; p.pad = 0; p.lg2U = 6; p.Umask = 63;
  conv_mfma<2, -1, false, false, 0, false><<<dim3(128, 4), 256, 0, stream>>>(p);

  // ---- VQ ----
  emb_prep<<<2048, 256, 0, stream>>>(emb, e1g, e2g, nrm);
  vq_mfma<<<1024, 256, 0, stream>>>(z1g, z2g, e1g, e2g, nrm, pbest, pidx);
  merge_kernel<<<64, 256, 0, stream>>>(pbest, pidx, vidx, out + idx_off, lacc);
  loss_kernel<<<4096, 256, 0, stream>>>(z1g, z2g, emb, vidx, lacc);
  fin_kernel<<<1, 64, 0, stream>>>(lacc, out, loss_off);

  // ---- decoder ----
  // dec0 (U=64, tiles straddle batches): split kernels with e1g[vidx] gather
  p.inH = e1g; p.inL = nullptr; p.w = dw0; p.bias = db0;
  p.outH = d1h; p.outL = nullptr; p.vidx = vidx;
  p.Ci = 256; p.lg2Ci = 8; p.Ti = 64; p.Co = 256; p.To = 128; p.KWO = 3;
  p.lg2U = 6; p.Umask = 63;
  p.K2 = 256; conv_mfma<1, 0, true, true, 1, false><<<dim3(128, 4), 256, 0, stream>>>(p);
  p.K2 = 512; conv_mfma<1, 1, true, true, 1, false><<<dim3(128, 4), 256, 0, stream>>>(p);

  // dec1..dec3: parity-merged
  CPD d;
  d.inH = d1h; d.w = dw1; d.bias = db1; d.outF = nullptr; d.outH = d2h;
  d.Ci = 256; d.Ti = 128; d.Co = 128; d.To = 256; d.lg2U = 7; d.Umask = 127;
  conv_dec<true, false><<<dim3(256, 2), 256, 0, stream>>>(d);

  d.inH = d2h; d.w = dw2; d.bias = db2; d.outH = d3h;
  d.Ci = 128; d.Ti = 256; d.Co = 64; d.To = 512; d.lg2U = 8; d.Umask = 255;
  conv_dec<true, false><<<dim3(512, 1), 256, 0, stream>>>(d);

  d.inH = d3h; d.w = dw3; d.bias = db3; d.outF = out; d.outH = nullptr;
  d.Ci = 64; d.Ti = 512; d.Co = 32; d.To = 1024; d.lg2U = 9; d.Umask = 511;
  conv_dec<false, true><<<dim3(1024, 1), 256, 0, stream>>>(d);
}

// Round 8
// 746.714 us; speedup vs baseline: 1.6125x; 1.2146x over previous
//
#include <hip/hip_runtime.h>

// ---------------------------------------------------------------------------
// VQ-VAE forward. R8: vq_mfma rebuilt around register-resident z.
//  - z A-fragments are contiguous 16B in global -> loaded ONCE per block
//    directly into 128 VGPRs (no LDS for z, no 8x re-staging).
//  - inner loop stages only e: double-buffered LDS (one barrier/step),
//    prefetch into 4 named uint4 regs (fully-unrolled kb -> no spill).
//  - XCD mapping flipped: seg = bid & 7 pins a 1 MB e-slice per XCD (e is
//    now the only re-read stream -> L2-resident); z streams once (134 MB).
//  - FP order (kb -> ct -> rt -> a1b1,a2b1,a1b2) identical to R7: argmin-safe.
// Convs / losses / decoder unchanged from R7.
// ---------------------------------------------------------------------------

typedef _Float16 half8 __attribute__((ext_vector_type(8)));
typedef _Float16 half4v __attribute__((ext_vector_type(4)));
typedef float f32x4 __attribute__((ext_vector_type(4)));

struct CP2 {
  const _Float16* inH; const _Float16* inL; const float* inF;
  const float* w; const float* bias;
  float* outF; _Float16* outH; _Float16* outL;
  const int* vidx;
  int Ci, lg2Ci, Ti, Co, To, KWO, K2, stride, pad, lg2U, Umask;
};

template<int SP, int PAR, bool GATHER, bool RELU, int OM, bool INF32>
__global__ __launch_bounds__(256, SP == 2 ? 3 : 4) void conv_mfma(CP2 p) {
  __shared__ _Float16 As[SP * 128 * 40];
  __shared__ _Float16 Bs[SP * 64 * 40];
  const int tid = threadIdx.x;
  const int wv = tid >> 6;
  const int lane = tid & 63;
  const int m = lane & 15, q = lane >> 4;
  const int btbase = blockIdx.x * 128;
  const int cobase = blockIdx.y * 64;
  f32x4 acc[2][4];
#pragma unroll
  for (int i = 0; i < 2; ++i)
#pragma unroll
    for (int j = 0; j < 4; ++j) acc[i][j] = {0.f, 0.f, 0.f, 0.f};

  const int nkb = p.K2 >> 5;
  for (int kb = 0; kb < nkb; ++kb) {
    const int k0 = kb << 5;
    const int tap = k0 >> p.lg2Ci;
    const int ci0 = k0 & (p.Ci - 1);
    int ko, dt;
    if (PAR == 0)      { ko = 1;       dt = 0; }
    else if (PAR == 1) { ko = 2 * tap; dt = tap; }
    else               { ko = tap;     dt = tap - p.pad; }
    __syncthreads();
    {
      const int cc = tid >> 2, g = tid & 3;
      const int cog = cobase + cc;
      const bool okc = cog < p.Co;
      float wvv[8];
#pragma unroll
      for (int j = 0; j < 8; ++j)
        wvv[j] = okc ? p.w[(cog * p.Ci + ci0 + g * 8 + j) * p.KWO + ko] : 0.f;
      half8 hv, lv;
#pragma unroll
      for (int j = 0; j < 8; ++j) {
        hv[j] = (_Float16)wvv[j];
        if (SP == 2) lv[j] = (_Float16)(wvv[j] - (float)hv[j]);
      }
      *(half8*)&Bs[cc * 40 + g * 8] = hv;
      if (SP == 2) *(half8*)&Bs[64 * 40 + cc * 40 + g * 8] = lv;
    }
#pragma unroll
    for (int it = 0; it < 2; ++it) {
      const int r = it * 64 + (tid >> 2), g = tid & 3;
      const int bt = btbase + r;
      const int b = bt >> p.lg2U, u = bt & p.Umask;
      const int tin = (PAR < 0) ? u * p.stride + dt : u + dt;
      const bool ok = (tin >= 0) && (tin < p.Ti);
      int ai;
      if (GATHER) {
        const int er = ok ? p.vidx[b * p.Ti + tin] : 0;
        ai = er * 256 + ci0 + g * 8;
      } else {
        ai = (b * p.Ti + tin) * p.Ci + ci0 + g * 8;
      }
      if (INF32) {
        float vv[8];
#pragma unroll
        for (int j = 0; j < 8; ++j) vv[j] = ok ? p.inF[ai + j] : 0.f;
        half8 hv, lv;
#pragma unroll
        for (int j = 0; j < 8; ++j) {
          hv[j] = (_Float16)vv[j];
          lv[j] = (_Float16)(vv[j] - (float)hv[j]);
        }
        *(half8*)&As[r * 40 + g * 8] = hv;
        if (SP == 2) *(half8*)&As[128 * 40 + r * 40 + g * 8] = lv;
      } else {
        const uint4 z = {0u, 0u, 0u, 0u};
        const uint4 vh = ok ? *(const uint4*)&p.inH[ai] : z;
        *(uint4*)&As[r * 40 + g * 8] = vh;
        if (SP == 2) {
          const uint4 vl = ok ? *(const uint4*)&p.inL[ai] : z;
          *(uint4*)&As[128 * 40 + r * 40 + g * 8] = vl;
        }
      }
    }
    __syncthreads();
    half8 a1[2], a2[2];
#pragma unroll
    for (int rt = 0; rt < 2; ++rt) {
      const int row = wv * 32 + rt * 16 + m;
      a1[rt] = *(const half8*)&As[row * 40 + q * 8];
      if (SP == 2) a2[rt] = *(const half8*)&As[128 * 40 + row * 40 + q * 8];
    }
#pragma unroll
    for (int ct = 0; ct < 4; ++ct) {
      const half8 b1 = *(const half8*)&Bs[(ct * 16 + m) * 40 + q * 8];
      half8 b2;
      if (SP == 2) b2 = *(const half8*)&Bs[64 * 40 + (ct * 16 + m) * 40 + q * 8];
#pragma unroll
      for (int rt = 0; rt < 2; ++rt) {
        acc[rt][ct] = __builtin_amdgcn_mfma_f32_16x16x32_f16(a1[rt], b1, acc[rt][ct], 0, 0, 0);
        if (SP == 2) {
          acc[rt][ct] = __builtin_amdgcn_mfma_f32_16x16x32_f16(a2[rt], b1, acc[rt][ct], 0, 0, 0);
          acc[rt][ct] = __builtin_amdgcn_mfma_f32_16x16x32_f16(a1[rt], b2, acc[rt][ct], 0, 0, 0);
        }
      }
    }
  }
#pragma unroll
  for (int ct = 0; ct < 4; ++ct) {
    const int co = cobase + ct * 16 + m;
    if (co < p.Co) {
      const float bv = p.bias[co];
#pragma unroll
      for (int rt = 0; rt < 2; ++rt) {
#pragma unroll
        for (int j = 0; j < 4; ++j) {
          const int row = btbase + wv * 32 + rt * 16 + q * 4 + j;
          const int b = row >> p.lg2U, u = row & p.Umask;
          float v = acc[rt][ct][j] + bv;
          if (RELU) v = fmaxf(v, 0.f);
          const int t = (PAR < 0) ? u : 2 * u + PAR;
          const int oi = (b * p.To + t) * p.Co + co;
          if (OM == 3) {
            p.outF[oi] = v;
          } else if (OM == 1) {
            p.outH[oi] = (_Float16)v;
          } else {
            const _Float16 h = (_Float16)v;
            const _Float16 l = (_Float16)(v - (float)h);
            p.outH[oi] = h; p.outL[oi] = l;
          }
        }
      }
    }
  }
}

struct CPD {
  const _Float16* inH; const float* w; const float* bias;
  float* outF; _Float16* outH;
  int Ci, Ti, Co, To, lg2U, Umask;
};

template<bool RELU, bool F32OUT>
__global__ __launch_bounds__(256, 4) void conv_dec(CPD p) {
  __shared__ _Float16 As[129 * 40];
  __shared__ _Float16 Bs[3 * 64 * 40];
  const int tid = threadIdx.x;
  const int wv = tid >> 6;
  const int lane = tid & 63;
  const int m = lane & 15, q = lane >> 4;
  const int btbase = blockIdx.x * 128;
  const int cobase = blockIdx.y * 64;
  const int b0 = btbase >> p.lg2U;
  const int u0 = btbase & p.Umask;
  f32x4 aE[2][4], aO[2][4];
#pragma unroll
  for (int i = 0; i < 2; ++i)
#pragma unroll
    for (int j = 0; j < 4; ++j) { aE[i][j] = {0.f,0.f,0.f,0.f}; aO[i][j] = {0.f,0.f,0.f,0.f}; }

  const int nkb = p.Ci >> 5;
  for (int kb = 0; kb < nkb; ++kb) {
    const int ci0 = kb << 5;
    __syncthreads();
#pragma unroll
    for (int tap = 0; tap < 3; ++tap) {
      const int cc = tid >> 2, g = tid & 3;
      const int cog = cobase + cc;
      half8 hv;
#pragma unroll
      for (int j = 0; j < 8; ++j) {
        const float wv_ = (cog < p.Co) ? p.w[(cog * p.Ci + ci0 + g * 8 + j) * 3 + tap] : 0.f;
        hv[j] = (_Float16)wv_;
      }
      *(half8*)&Bs[tap * 2560 + cc * 40 + g * 8] = hv;
    }
#pragma unroll
    for (int i = 0; i < 3; ++i) {
      const int e = i * 256 + tid;
      const int r = e >> 2, g = e & 3;
      if (r < 129) {
        const int ur = u0 + r;
        const bool ok = ur < p.Ti;
        const uint4 z = {0u, 0u, 0u, 0u};
        const uint4 v = ok ? *(const uint4*)&p.inH[(b0 * p.Ti + ur) * p.Ci + ci0 + g * 8] : z;
        *(uint4*)&As[r * 40 + g * 8] = v;
      }
    }
    __syncthreads();
    half8 a0[2], a1s[2];
#pragma unroll
    for (int rt = 0; rt < 2; ++rt) {
      const int row = wv * 32 + rt * 16 + m;
      a0[rt]  = *(const half8*)&As[row * 40 + q * 8];
      a1s[rt] = *(const half8*)&As[(row + 1) * 40 + q * 8];
    }
#pragma unroll
    for (int ct = 0; ct < 4; ++ct) {
      const int c = ct * 16 + m;
      const half8 w0 = *(const half8*)&Bs[c * 40 + q * 8];
      const half8 w1 = *(const half8*)&Bs[2560 + c * 40 + q * 8];
      const half8 w2 = *(const half8*)&Bs[5120 + c * 40 + q * 8];
#pragma unroll
      for (int rt = 0; rt < 2; ++rt) {
        aE[rt][ct] = __builtin_amdgcn_mfma_f32_16x16x32_f16(a0[rt],  w1, aE[rt][ct], 0, 0, 0);
        aO[rt][ct] = __builtin_amdgcn_mfma_f32_16x16x32_f16(a0[rt],  w0, aO[rt][ct], 0, 0, 0);
        aO[rt][ct] = __builtin_amdgcn_mfma_f32_16x16x32_f16(a1s[rt], w2, aO[rt][ct], 0, 0, 0);
      }
    }
  }
#pragma unroll
  for (int ct = 0; ct < 4; ++ct) {
    const int co = cobase + ct * 16 + m;
    if (co < p.Co) {
      const float bv = p.bias[co];
#pragma unroll
      for (int rt = 0; rt < 2; ++rt) {
#pragma unroll
        for (int j = 0; j < 4; ++j) {
          const int u = u0 + wv * 32 + rt * 16 + q * 4 + j;
          float vE = aE[rt][ct][j] + bv;
          float vO = aO[rt][ct][j] + bv;
          if (RELU) { vE = fmaxf(vE, 0.f); vO = fmaxf(vO, 0.f); }
          const int oiE = (b0 * p.To + 2 * u) * p.Co + co;
          const int oiO = oiE + p.Co;
          if (F32OUT) { p.outF[oiE] = vE; p.outF[oiO] = vO; }
          else        { p.outH[oiE] = (_Float16)vE; p.outH[oiO] = (_Float16)vO; }
        }
      }
    }
  }
}

__global__ __launch_bounds__(256) void emb_prep(const float* __restrict__ emb,
                                                _Float16* __restrict__ hi,
                                                _Float16* __restrict__ lo,
                                                float* __restrict__ nrm) {
  const int k = blockIdx.x * 4 + (threadIdx.x >> 6);
  const int lane = threadIdx.x & 63;
  const int i = k * 64 + lane;
  const float4 v = ((const float4*)emb)[i];
  half4v a, b;
  a.x = (_Float16)v.x; b.x = (_Float16)(v.x - (float)a.x);
  a.y = (_Float16)v.y; b.y = (_Float16)(v.y - (float)a.y);
  a.z = (_Float16)v.z; b.z = (_Float16)(v.z - (float)a.z);
  a.w = (_Float16)v.w; b.w = (_Float16)(v.w - (float)a.w);
  ((half4v*)hi)[i] = a;
  ((half4v*)lo)[i] = b;
  double s = (double)v.x * v.x + (double)v.y * v.y +
             (double)v.z * v.z + (double)v.w * v.w;
  for (int off = 32; off; off >>= 1) s += __shfl_down(s, off);
  if (lane == 0) nrm[k] = (float)s;
}

// VQ argmin, R8: register-resident z, e-only dbuf LDS staging, seg-per-XCD.
__global__ __launch_bounds__(256, 2) void vq_mfma(const _Float16* __restrict__ z1g,
                                                  const _Float16* __restrict__ z2g,
                                                  const _Float16* __restrict__ e1g,
                                                  const _Float16* __restrict__ e2g,
                                                  const float* __restrict__ nrm,
                                                  float* __restrict__ pbest,
                                                  int* __restrict__ pidx) {
  __shared__ _Float16 es[2 * 2 * 128 * 40];   // [buf][arr] 40 KB
  const int tid = threadIdx.x;
  const int lane = tid & 63;
  const int w = tid >> 6;
  const int m = lane & 15;
  const int q = lane >> 4;
  const int seg = blockIdx.x & 7, rb = blockIdx.x >> 3;   // XCD = bid%8 = seg
  const int rbase = rb * 128;
  const int w32 = w * 32;

  // z fragments, loaded once (contiguous 16B each; bit-identical operands)
  half8 za[2][8], zb[2][8];
#pragma unroll
  for (int rt = 0; rt < 2; ++rt)
#pragma unroll
    for (int kb = 0; kb < 8; ++kb) {
      const int zi = (rbase + w32 + rt * 16 + m) * 256 + kb * 32 + q * 8;
      za[rt][kb] = *(const half8*)&z1g[zi];
      zb[rt][kb] = *(const half8*)&z2g[zi];
    }

  float best[8]; int bk[8];
#pragma unroll
  for (int i = 0; i < 8; ++i) { best[i] = 3.4e38f; bk[i] = 0; }

  const int c  = tid >> 1;            // e-staging: code row
  const int sh = (tid & 1) * 16;      // half-offset within 32-dim chunk
  const int ebase = (seg * 1024 + c) * 256 + sh;
  const int lbase = c * 40 + sh;

  uint4 p1a, p1b, p2a, p2b;           // prefetch regs (named -> no spill)
  {
    const int eg = ebase;             // cc=0, kb=0
    p1a = *(const uint4*)&e1g[eg];  p1b = *(const uint4*)&e1g[eg + 8];
    p2a = *(const uint4*)&e2g[eg];  p2b = *(const uint4*)&e2g[eg + 8];
  }

  f32x4 acc[2][8];
  for (int cc = 0; cc < 8; ++cc) {
    const int cbase = seg * 1024 + cc * 128;
#pragma unroll
    for (int rt = 0; rt < 2; ++rt)
#pragma unroll
      for (int ct = 0; ct < 8; ++ct) acc[rt][ct] = {0.f, 0.f, 0.f, 0.f};
#pragma unroll
    for (int kb = 0; kb < 8; ++kb) {
      const int buf = kb & 1;                       // compile-time per body
      _Float16* e1s = &es[(buf * 2 + 0) * 5120];
      _Float16* e2s = &es[(buf * 2 + 1) * 5120];
      // write prefetched step into buf (other buffer than currently read)
      *(uint4*)&e1s[lbase]     = p1a;
      *(uint4*)&e1s[lbase + 8] = p1b;
      *(uint4*)&e2s[lbase]     = p2a;
      *(uint4*)&e2s[lbase + 8] = p2b;
      // issue next step's loads (in flight across barrier + MFMA)
      if (kb < 7) {
        const int eg = ebase + cc * 128 * 256 + (kb + 1) * 32;
        p1a = *(const uint4*)&e1g[eg];  p1b = *(const uint4*)&e1g[eg + 8];
        p2a = *(const uint4*)&e2g[eg];  p2b = *(const uint4*)&e2g[eg + 8];
      } else if (cc < 7) {
        const int eg = ebase + (cc + 1) * 128 * 256;
        p1a = *(const uint4*)&e1g[eg];  p1b = *(const uint4*)&e1g[eg + 8];
        p2a = *(const uint4*)&e2g[eg];  p2b = *(const uint4*)&e2g[eg + 8];
      }
      __syncthreads();
#pragma unroll
      for (int ct = 0; ct < 8; ++ct) {
        const int cr = ct * 16 + m;
        const half8 b1 = *(const half8*)&e1s[cr * 40 + q * 8];
        const half8 b2 = *(const half8*)&e2s[cr * 40 + q * 8];
#pragma unroll
        for (int rt = 0; rt < 2; ++rt) {
          acc[rt][ct] = __builtin_amdgcn_mfma_f32_16x16x32_f16(za[rt][kb], b1, acc[rt][ct], 0, 0, 0);
          acc[rt][ct] = __builtin_amdgcn_mfma_f32_16x16x32_f16(zb[rt][kb], b1, acc[rt][ct], 0, 0, 0);
          acc[rt][ct] = __builtin_amdgcn_mfma_f32_16x16x32_f16(za[rt][kb], b2, acc[rt][ct], 0, 0, 0);
        }
      }
    }
    // epilogue: dist = |e|^2 - 2 z.e, per-row best (k ascending)
#pragma unroll
    for (int ct = 0; ct < 8; ++ct) {
      const int k = cbase + ct * 16 + m;
      const float nv = nrm[k];
#pragma unroll
      for (int rt = 0; rt < 2; ++rt)
#pragma unroll
        for (int rg = 0; rg < 4; ++rg) {
          const float d = nv - 2.f * acc[rt][ct][rg];
          const int slot = rt * 4 + rg;
          if (d < best[slot] || (d == best[slot] && k < bk[slot])) {
            best[slot] = d; bk[slot] = k;
          }
        }
    }
  }
#pragma unroll
  for (int slot = 0; slot < 8; ++slot) {
    float bv = best[slot]; int kv = bk[slot];
    for (int off = 1; off < 16; off <<= 1) {
      const float ob = __shfl_xor(bv, off);
      const int ok = __shfl_xor(kv, off);
      if (ob < bv || (ob == bv && ok < kv)) { bv = ob; kv = ok; }
    }
    if (m == 0) {
      const int row = rbase + w32 + (slot >> 2) * 16 + q * 4 + (slot & 3);
      pbest[seg * 16384 + row] = bv;
      pidx[seg * 16384 + row] = kv;
    }
  }
}

__global__ void merge_kernel(const float* __restrict__ pbest, const int* __restrict__ pidx,
                             int* __restrict__ vidx, float* __restrict__ out_idx,
                             float* __restrict__ lacc) {
  const int n = blockIdx.x * 256 + threadIdx.x;
  float bv = pbest[n]; int kv = pidx[n];
#pragma unroll
  for (int s = 1; s < 8; ++s) {
    const float ob = pbest[s * 16384 + n];
    const int ok = pidx[s * 16384 + n];
    if (ob < bv || (ob == bv && ok < kv)) { bv = ob; kv = ok; }
  }
  vidx[n] = kv;
  out_idx[n] = (float)kv;
  if (n == 0) *lacc = 0.f;
}

__global__ __launch_bounds__(256) void loss_kernel(const _Float16* __restrict__ z1g,
                                                   const _Float16* __restrict__ z2g,
                                                   const float* __restrict__ emb,
                                                   const int* __restrict__ vidx,
                                                   float* __restrict__ lacc) {
  const int g4 = blockIdx.x * 256 + threadIdx.x;
  const int e0 = g4 * 4;
  const int n = e0 >> 8, c = e0 & 255;
  const half4v a = ((const half4v*)z1g)[g4];
  const half4v b = ((const half4v*)z2g)[g4];
  const float4 q4 = *(const float4*)&emb[vidx[n] * 256 + c];
  const float dx = ((float)a.x + (float)b.x) - q4.x;
  const float dy = ((float)a.y + (float)b.y) - q4.y;
  const float dz = ((float)a.z + (float)b.z) - q4.z;
  const float dw = ((float)a.w + (float)b.w) - q4.w;
  float s = dx * dx + dy * dy + dz * dz + dw * dw;
  for (int off = 32; off; off >>= 1) s += __shfl_down(s, off);
  __shared__ float red[4];
  if ((threadIdx.x & 63) == 0) red[threadIdx.x >> 6] = s;
  __syncthreads();
  if (threadIdx.x == 0) atomicAdd(lacc, red[0] + red[1] + red[2] + red[3]);
}

__global__ void fin_kernel(const float* __restrict__ lacc, float* __restrict__ out, int loff) {
  if (threadIdx.x == 0) {
    const float l = *lacc * (1.f / 4194304.f);
    out[loff] = l;
    out[loff + 1] = l;
  }
}

extern "C" void kernel_launch(void* const* d_in, const int* in_sizes, int n_in,
                              void* d_out, int out_size, void* d_ws, size_t ws_size,
                              hipStream_t stream) {
  const float* x   = (const float*)d_in[0];
  const float* ew0 = (const float*)d_in[1];  const float* eb0 = (const float*)d_in[2];
  const float* ew1 = (const float*)d_in[3];  const float* eb1 = (const float*)d_in[4];
  const float* ew2 = (const float*)d_in[5];  const float* eb2 = (const float*)d_in[6];
  const float* pw  = (const float*)d_in[7];  const float* pb  = (const float*)d_in[8];
  const float* emb = (const float*)d_in[9];
  const float* dw0 = (const float*)d_in[10]; const float* db0 = (const float*)d_in[11];
  const float* dw1 = (const float*)d_in[12]; const float* db1 = (const float*)d_in[13];
  const float* dw2 = (const float*)d_in[14]; const float* db2 = (const float*)d_in[15];
  const float* dw3 = (const float*)d_in[16]; const float* db3 = (const float*)d_in[17];
  float* ws  = (float*)d_ws;
  float* out = (float*)d_out;

  const int A0 = 0, B0 = 4194304, C0 = 8388608, TL = 12582912;
  _Float16* h1h = (_Float16*)(ws + B0);
  _Float16* h1l = h1h + 4194304;
  _Float16* h2h = (_Float16*)(ws + A0);
  _Float16* h2l = h2h + 4194304;
  _Float16* h3h = (_Float16*)(ws + B0);
  _Float16* h3l = h3h + 4194304;
  _Float16* z1g = (_Float16*)(ws + A0);
  _Float16* z2g = z1g + 4194304;
  _Float16* e1g = (_Float16*)(ws + B0);
  _Float16* e2g = e1g + 2097152;
  float* pbest = ws + B0 + 2097152;
  int*   pidx  = (int*)(ws + B0 + 2097152 + 131072);
  _Float16* d1h = (_Float16*)(ws + C0);
  _Float16* d2h = (_Float16*)(ws + A0);
  _Float16* d3h = (_Float16*)(ws + B0);
  float* nrm  = ws + TL;
  int*   vidx = (int*)(ws + TL + 8192);
  float* lacc = ws + TL + 8192 + 16384;

  const int idx_off  = out_size - 16384;
  const int loss_off = out_size - 16386;

  CP2 p; p.vidx = nullptr; p.inF = nullptr; p.inH = nullptr; p.inL = nullptr;
  p.outF = nullptr; p.outH = nullptr; p.outL = nullptr;

  // ---- encoder (3-pass f16 split MFMA; enc0 splits x inline) ----
  p.inF = x; p.w = ew0; p.bias = eb0; p.outH = h1h; p.outL = h1l;
  p.Ci = 32; p.lg2Ci = 5; p.Ti = 512; p.Co = 64; p.To = 256; p.KWO = 3;
  p.K2 = 96; p.stride = 2; p.pad = 1; p.lg2U = 8; p.Umask = 255;
  conv_mfma<2, -1, false, true, 0, true><<<dim3(512, 1), 256, 0, stream>>>(p);

  p.inF = nullptr;
  p.inH = h1h; p.inL = h1l; p.w = ew1; p.bias = eb1; p.outH = h2h; p.outL = h2l;
  p.Ci = 64; p.lg2Ci = 6; p.Ti = 256; p.Co = 128; p.To = 128; p.K2 = 192;
  p.lg2U = 7; p.Umask = 127;
  conv_mfma<2, -1, false, true, 0, false><<<dim3(256, 2), 256, 0, stream>>>(p);

  p.inH = h2h; p.inL = h2l; p.w = ew2; p.bias = eb2; p.outH = h3h; p.outL = h3l;
  p.Ci = 128; p.lg2Ci = 7; p.Ti = 128; p.Co = 256; p.To = 64; p.K2 = 384;
  p.lg2U = 6; p.Umask = 63;
  conv_mfma<2, -1, false, true, 0, false><<<dim3(128, 4), 256, 0, stream>>>(p);

  p.inH = h3h; p.inL = h3l; p.w = pw; p.bias = pb;
  p.outH = z1g; p.outL = z2g;
  p.Ci = 256; p.lg2Ci = 8; p.Ti = 64; p.Co = 256; p.To = 64; p.KWO = 1;
  p.K2 = 256; p.stride = 1; p.pad = 0; p.lg2U = 6; p.Umask = 63;
  conv_mfma<2, -1, false, false, 0, false><<<dim3(128, 4), 256, 0, stream>>>(p);

  // ---- VQ ----
  emb_prep<<<2048, 256, 0, stream>>>(emb, e1g, e2g, nrm);
  vq_mfma<<<1024, 256, 0, stream>>>(z1g, z2g, e1g, e2g, nrm, pbest, pidx);
  merge_kernel<<<64, 256, 0, stream>>>(pbest, pidx, vidx, out + idx_off, lacc);
  loss_kernel<<<4096, 256, 0, stream>>>(z1g, z2g, emb, vidx, lacc);
  fin_kernel<<<1, 64, 0, stream>>>(lacc, out, loss_off);

  // ---- decoder ----
  p.inH = e1g; p.inL = nullptr; p.w = dw0; p.bias = db0;
  p.outH = d1h; p.outL = nullptr; p.vidx = vidx;
  p.Ci = 256; p.lg2Ci = 8; p.Ti = 64; p.Co = 256; p.To = 128; p.KWO = 3;
  p.lg2U = 6; p.Umask = 63;
  p.K2 = 256; conv_mfma<1, 0, true, true, 1, false><<<dim3(128, 4), 256, 0, stream>>>(p);
  p.K2 = 512; conv_mfma<1, 1, true, true, 1, false><<<dim3(128, 4), 256, 0, stream>>>(p);

  CPD d;
  d.inH = d1h; d.w = dw1; d.bias = db1; d.outF = nullptr; d.outH = d2h;
  d.Ci = 256; d.Ti = 128; d.Co = 128; d.To = 256; d.lg2U = 7; d.Umask = 127;
  conv_dec<true, false><<<dim3(256, 2), 256, 0, stream>>>(d);

  d.inH = d2h; d.w = dw2; d.bias = db2; d.outH = d3h;
  d.Ci = 128; d.Ti = 256; d.Co = 64; d.To = 512; d.lg2U = 8; d.Umask = 255;
  conv_dec<true, false><<<dim3(512, 1), 256, 0, stream>>>(d);

  d.inH = d3h; d.w = dw3; d.bias = db3; d.outF = out; d.outH = nullptr;
  d.Ci = 64; d.Ti = 512; d.Co = 32; d.To = 1024; d.lg2U = 9; d.Umask = 511;
  conv_dec<false, true><<<dim3(1024, 1), 256, 0, stream>>>(d);
}